// Round 5
// baseline (38.602 us; speedup 1.0000x reference)
//
#include <hip/hip_runtime.h>

// N_TOTAL=10100, D=128, B=2048. F dense-stored, ~33 nnz/row (Poisson(32)+diag).
// Two kernels:
//  A (per batch row): scan F row (float4) -> compact (idx,w) into LDS (one
//    predicated atomic per chunk) -> zero-pad to KMAX=64 -> fixed-trip
//    fully-unrolled sparse aggregate (16 groups x 32 lanes, float4 E rows)
//    -> agg row to d_ws.
//  B (8 rows/block): out = agg @ W^T + bias. W read coalesced (float4),
//    32-lane shuffle reduce per output feature. W is L2-hot (64 KB).

#define NTOT 10100
#define NV4  2525     // NTOT/4 exact
#define DIM  128
#define CAP  256      // nnz ~ Poisson(32); dense fallback if exceeded
#define KMAX 64       // fixed-trip unroll bound; dynamic tail if cnt>KMAX
#define TPB  512
#define RB   8        // rows per block in kernel B

__global__ __launch_bounds__(TPB) void scan_agg_kernel(
    const int*   __restrict__ uids,
    const float* __restrict__ F,
    const float* __restrict__ E,
    float*       __restrict__ agg)
{
    __shared__ int   s_idx[CAP];
    __shared__ float s_w[CAP];
    __shared__ int   s_cnt;
    __shared__ float s_red[16][DIM];   // 8 KB partials

    const int row = blockIdx.x;
    const int tid = threadIdx.x;
    const int uid = uids[row];
    const float* Frow = F + (size_t)uid * NTOT;

    if (tid == 0) s_cnt = 0;
    __syncthreads();

    // ---- P1: float4 scan, single predicated atomic per nonzero chunk ----
    const float4* Frow4 = (const float4*)Frow;   // uid*40400 % 16 == 0
    for (int i = tid; i < NV4; i += TPB) {
        float4 v = Frow4[i];
        int n = i * 4;
        bool ba = v.x != 0.0f, bb = v.y != 0.0f, bc = v.z != 0.0f, bd = v.w != 0.0f;
        int  m  = (int)ba + (int)bb + (int)bc + (int)bd;
        if (m) {
            int p = atomicAdd(&s_cnt, m);
            if (p + m <= CAP) {
                if (ba) { s_idx[p] = n;     s_w[p] = v.x; ++p; }
                if (bb) { s_idx[p] = n + 1; s_w[p] = v.y; ++p; }
                if (bc) { s_idx[p] = n + 2; s_w[p] = v.z; ++p; }
                if (bd) { s_idx[p] = n + 3; s_w[p] = v.w; ++p; }
            }
        }
    }
    __syncthreads();

    const int cnt = s_cnt;
    // ---- zero-pad to KMAX so P2 has a fixed, fully-unrolled trip count ----
    for (int t = cnt + tid; t < KMAX; t += TPB) { s_idx[t] = 0; s_w[t] = 0.0f; }
    __syncthreads();

    // ---- P2: agg[d] = sum_k w_k * E[n_k][d]; 16 groups x 32 lanes ----
    const int g = tid >> 5;    // entry-group 0..15
    const int l = tid & 31;    // lane owns d = 4l..4l+3
    float4 acc = make_float4(0.f, 0.f, 0.f, 0.f);

    if (cnt <= CAP) {
        #pragma unroll
        for (int t = 0; t < KMAX / 16; ++t) {     // 4 independent gathers
            int   k = g + 16 * t;
            int   n = s_idx[k];
            float w = s_w[k];
            float4 ev = *(const float4*)(E + (size_t)n * DIM + l * 4);
            acc.x += w * ev.x; acc.y += w * ev.y;
            acc.z += w * ev.z; acc.w += w * ev.w;
        }
        for (int k = g + KMAX; k < cnt; k += 16) {  // rare dynamic tail
            int   n = s_idx[k];
            float w = s_w[k];
            float4 ev = *(const float4*)(E + (size_t)n * DIM + l * 4);
            acc.x += w * ev.x; acc.y += w * ev.y;
            acc.z += w * ev.z; acc.w += w * ev.w;
        }
    } else {
        // impossible-in-practice dense fallback (correctness net)
        for (int n = g; n < NTOT; n += 16) {
            float w = Frow[n];
            float4 ev = *(const float4*)(E + (size_t)n * DIM + l * 4);
            acc.x += w * ev.x; acc.y += w * ev.y;
            acc.z += w * ev.z; acc.w += w * ev.w;
        }
    }
    *(float4*)&s_red[g][l * 4] = acc;
    __syncthreads();

    if (tid < DIM) {
        float sum = 0.0f;
        #pragma unroll
        for (int gg = 0; gg < 16; ++gg) sum += s_red[gg][tid];
        agg[(size_t)row * DIM + tid] = sum;      // coalesced 512B store
    }
}

__global__ __launch_bounds__(TPB) void linear_kernel(
    const float* __restrict__ agg,
    const float* __restrict__ W,
    const float* __restrict__ bias,
    float*       __restrict__ out,
    int B)
{
    __shared__ float s_agg[RB][DIM];
    __shared__ float s_out[RB][DIM];

    const int tid  = threadIdx.x;
    const int base = blockIdx.x * RB;

    // stage agg tile (coalesced; rows beyond B read garbage but are not stored)
    for (int i = tid; i < RB * DIM; i += TPB) {
        int r = i >> 7;
        ((float*)s_agg)[i] = (base + r < B) ? agg[(size_t)base * DIM + i] : 0.0f;
    }
    __syncthreads();

    // out[r][j] = bias[j] + sum_d agg[r][d] * W[j][d]; coalesced W float4s
    const float4* W4 = (const float4*)W;
    #pragma unroll
    for (int q = 0; q < 8; ++q) {
        int i4 = tid + TPB * q;          // flat float4 index 0..4095
        float4 wv = W4[i4];
        int j  = i4 >> 5;
        int dd = (i4 & 31) * 4;
        #pragma unroll
        for (int r = 0; r < RB; ++r) {
            float4 ag = *(const float4*)&s_agg[r][dd];
            float p = wv.x * ag.x + wv.y * ag.y + wv.z * ag.z + wv.w * ag.w;
            p += __shfl_xor(p, 16);
            p += __shfl_xor(p, 8);
            p += __shfl_xor(p, 4);
            p += __shfl_xor(p, 2);
            p += __shfl_xor(p, 1);
            if ((tid & 31) == 0) s_out[r][j] = p;
        }
    }
    __syncthreads();

    for (int i = tid; i < RB * DIM; i += TPB) {
        int r = i >> 7, d = i & 127;
        if (base + r < B)
            out[(size_t)(base + r) * DIM + d] = bias[d] + s_out[r][d];
    }
}

extern "C" void kernel_launch(void* const* d_in, const int* in_sizes, int n_in,
                              void* d_out, int out_size, void* d_ws, size_t ws_size,
                              hipStream_t stream) {
    const int*   uids = (const int*)  d_in[0];
    const float* F    = (const float*)d_in[1];
    const float* E    = (const float*)d_in[2];
    const float* W    = (const float*)d_in[3];
    const float* bias = (const float*)d_in[4];
    float*       out  = (float*)d_out;
    float*       agg  = (float*)d_ws;            // 2048*128*4 = 1 MB << ws_size

    const int B = in_sizes[0];  // 2048
    scan_agg_kernel<<<B, TPB, 0, stream>>>(uids, F, E, agg);
    linear_kernel<<<(B + RB - 1) / RB, TPB, 0, stream>>>(agg, W, bias, out, B);
}

// Round 6
// 30.259 us; speedup vs baseline: 1.2757x; 1.2757x over previous
//
#include <hip/hip_runtime.h>

// N_TOTAL=10100, D=128, B=2048. F dense-stored, ~33 nnz/row.
// Fused, one batch row per block, TPB=256 (4 waves) so 6-8 blocks/CU stay
// resident in mixed phases -> F-streaming duty cycle stays high.
//   P1: float4 scan of F row (x2 unrolled), predicated single-atomic compaction
//   P2: sparse aggregate: 8 groups x 32 lanes, float4 E rows, x2 unrolled
//   P3: fused linear, coalesced flat W float4 reads + 32-lane shuffle reduce

#define NTOT 10100
#define NV4  2525     // NTOT/4 exact
#define DIM  128
#define CAP  256      // nnz ~ Poisson(32); dense fallback if exceeded
#define TPB  256

__global__ __launch_bounds__(TPB, 6) void friendship_kernel(
    const int*   __restrict__ uids,
    const float* __restrict__ F,
    const float* __restrict__ E,
    const float* __restrict__ W,
    const float* __restrict__ bias,
    float*       __restrict__ out)
{
    __shared__ int   s_idx[CAP];
    __shared__ float s_w[CAP];
    __shared__ int   s_cnt;
    __shared__ float s_red[8][DIM];   // 4 KB partials
    __shared__ float s_agg[DIM];
    __shared__ float s_out[DIM];

    const int row = blockIdx.x;
    const int tid = threadIdx.x;
    const int uid = uids[row];
    const float* Frow = F + (size_t)uid * NTOT;

    if (tid == 0) s_cnt = 0;
    __syncthreads();

    // ---- P1: float4 scan, x2 unrolled, one predicated atomic per hit chunk ----
    const float4* Frow4 = (const float4*)Frow;   // uid*40400 % 16 == 0
    int i = tid;
    for (; i + TPB < NV4; i += 2 * TPB) {
        float4 v0 = Frow4[i];
        float4 v1 = Frow4[i + TPB];
        {
            int n = i * 4;
            bool ba = v0.x != 0.0f, bb = v0.y != 0.0f, bc = v0.z != 0.0f, bd = v0.w != 0.0f;
            int  m  = (int)ba + (int)bb + (int)bc + (int)bd;
            if (m) {
                int p = atomicAdd(&s_cnt, m);
                if (p + m <= CAP) {
                    if (ba) { s_idx[p] = n;     s_w[p] = v0.x; ++p; }
                    if (bb) { s_idx[p] = n + 1; s_w[p] = v0.y; ++p; }
                    if (bc) { s_idx[p] = n + 2; s_w[p] = v0.z; ++p; }
                    if (bd) { s_idx[p] = n + 3; s_w[p] = v0.w; ++p; }
                }
            }
        }
        {
            int n = (i + TPB) * 4;
            bool ba = v1.x != 0.0f, bb = v1.y != 0.0f, bc = v1.z != 0.0f, bd = v1.w != 0.0f;
            int  m  = (int)ba + (int)bb + (int)bc + (int)bd;
            if (m) {
                int p = atomicAdd(&s_cnt, m);
                if (p + m <= CAP) {
                    if (ba) { s_idx[p] = n;     s_w[p] = v1.x; ++p; }
                    if (bb) { s_idx[p] = n + 1; s_w[p] = v1.y; ++p; }
                    if (bc) { s_idx[p] = n + 2; s_w[p] = v1.z; ++p; }
                    if (bd) { s_idx[p] = n + 3; s_w[p] = v1.w; ++p; }
                }
            }
        }
    }
    for (; i < NV4; i += TPB) {
        float4 v = Frow4[i];
        int n = i * 4;
        bool ba = v.x != 0.0f, bb = v.y != 0.0f, bc = v.z != 0.0f, bd = v.w != 0.0f;
        int  m  = (int)ba + (int)bb + (int)bc + (int)bd;
        if (m) {
            int p = atomicAdd(&s_cnt, m);
            if (p + m <= CAP) {
                if (ba) { s_idx[p] = n;     s_w[p] = v.x; ++p; }
                if (bb) { s_idx[p] = n + 1; s_w[p] = v.y; ++p; }
                if (bc) { s_idx[p] = n + 2; s_w[p] = v.z; ++p; }
                if (bd) { s_idx[p] = n + 3; s_w[p] = v.w; ++p; }
            }
        }
    }
    __syncthreads();

    const int cnt = s_cnt;
    const int g = tid >> 5;    // entry-group 0..7
    const int l = tid & 31;    // lane owns d = 4l..4l+3

    // ---- P2: agg[d] = sum_k w_k * E[n_k][d]; x2 unrolled ----
    float4 acc = make_float4(0.f, 0.f, 0.f, 0.f);
    if (cnt <= CAP) {
        int k = g;
        for (; k + 8 < cnt; k += 16) {
            int   n0 = s_idx[k];     float w0 = s_w[k];
            int   n1 = s_idx[k + 8]; float w1 = s_w[k + 8];
            float4 e0 = *(const float4*)(E + (size_t)n0 * DIM + l * 4);
            float4 e1 = *(const float4*)(E + (size_t)n1 * DIM + l * 4);
            acc.x += w0 * e0.x; acc.y += w0 * e0.y; acc.z += w0 * e0.z; acc.w += w0 * e0.w;
            acc.x += w1 * e1.x; acc.y += w1 * e1.y; acc.z += w1 * e1.z; acc.w += w1 * e1.w;
        }
        for (; k < cnt; k += 8) {
            int   n = s_idx[k];
            float w = s_w[k];
            float4 ev = *(const float4*)(E + (size_t)n * DIM + l * 4);
            acc.x += w * ev.x; acc.y += w * ev.y; acc.z += w * ev.z; acc.w += w * ev.w;
        }
    } else {
        for (int n = g; n < NTOT; n += 8) {   // never taken; correctness net
            float w = Frow[n];
            float4 ev = *(const float4*)(E + (size_t)n * DIM + l * 4);
            acc.x += w * ev.x; acc.y += w * ev.y; acc.z += w * ev.z; acc.w += w * ev.w;
        }
    }
    *(float4*)&s_red[g][l * 4] = acc;
    __syncthreads();

    if (tid < DIM) {
        float sum = 0.0f;
        #pragma unroll
        for (int gg = 0; gg < 8; ++gg) sum += s_red[gg][tid];
        s_agg[tid] = sum;
    }
    __syncthreads();

    // ---- P3: out[j] = bias[j] + sum_d agg[d]*W[j][d]; coalesced W ----
    const float4* W4 = (const float4*)W;
    #pragma unroll
    for (int q = 0; q < 16; ++q) {
        int i4 = tid + TPB * q;          // flat float4 index 0..4095
        float4 wv = W4[i4];              // fully coalesced, L2-hot
        int j  = i4 >> 5;
        int dd = (i4 & 31) * 4;
        float4 ag = *(const float4*)&s_agg[dd];
        float p = wv.x * ag.x + wv.y * ag.y + wv.z * ag.z + wv.w * ag.w;
        p += __shfl_xor(p, 16);
        p += __shfl_xor(p, 8);
        p += __shfl_xor(p, 4);
        p += __shfl_xor(p, 2);
        p += __shfl_xor(p, 1);
        if ((tid & 31) == 0) s_out[j] = p;
    }
    __syncthreads();
    if (tid < DIM)
        out[(size_t)row * DIM + tid] = bias[tid] + s_out[tid];
}

extern "C" void kernel_launch(void* const* d_in, const int* in_sizes, int n_in,
                              void* d_out, int out_size, void* d_ws, size_t ws_size,
                              hipStream_t stream) {
    const int*   uids = (const int*)  d_in[0];
    const float* F    = (const float*)d_in[1];
    const float* E    = (const float*)d_in[2];
    const float* W    = (const float*)d_in[3];
    const float* bias = (const float*)d_in[4];
    float*       out  = (float*)d_out;

    const int B = in_sizes[0];  // 2048
    friendship_kernel<<<B, TPB, 0, stream>>>(uids, F, E, W, bias, out);
}